// Round 3
// baseline (121.434 us; speedup 1.0000x reference)
//
#include <hip/hip_runtime.h>

#define IGNORE_LABEL (-100)

typedef float f32x4 __attribute__((ext_vector_type(4)));  // native vector: OK for nontemporal builtins

// d_out layout (flat float32): [P*128 proj | P idx passthrough | V counts]
//
// 32 lanes cooperate on one pixel row (32 x f32x4 = 512 B, fully coalesced).
// proj/idx_out stores are NONTEMPORAL (nt flag): write-once streams bypass
// L2/L3, preserving the 51 MB feature table in Infinity Cache so the random
// gathers hit L3 instead of re-fetching from HBM.
__global__ void RaycastFeatures_42597485641917_kernel(
        const f32x4* __restrict__ feat,   // [V][32] f32x4 view of [V][128] f32
        const int*   __restrict__ idx,    // [P]
        f32x4*       __restrict__ proj,   // [P][32] f32x4 view
        float*       __restrict__ idx_out,// [P]
        float*       __restrict__ counts, // [V], pre-zeroed
        int P) {
    const int tid  = blockIdx.x * blockDim.x + threadIdx.x;
    const int lane = tid & 31;
    const int grp0 = tid >> 5;
    const int ngrp = (gridDim.x * blockDim.x) >> 5;

    for (int p = grp0; p < P; p += ngrp) {
        const int  v     = __builtin_nontemporal_load(&idx[p]);  // read-once stream
        const bool valid = (v != IGNORE_LABEL);

        if (lane == 0) {
            __builtin_nontemporal_store((float)v, &idx_out[p]);
            if (valid) atomicAdd(&counts[v], 1.0f);
        }

        f32x4 val = (f32x4)(0.f);
        if (valid) val = feat[(size_t)v * 32 + lane];   // cached: table stays L3-resident
        __builtin_nontemporal_store(val, &proj[(size_t)p * 32 + lane]);
    }
}

extern "C" void kernel_launch(void* const* d_in, const int* in_sizes, int n_in,
                              void* d_out, int out_size, void* d_ws, size_t ws_size,
                              hipStream_t stream) {
    const float* feat = (const float*)d_in[0];   // [V,128] f32
    const int*   idx  = (const int*)d_in[1];     // [B,NV,H,W] i32 flattened

    const int D = 128;
    const int V = in_sizes[0] / D;     // 100000
    const int P = in_sizes[1];         // 614400

    float* out     = (float*)d_out;
    f32x4* proj    = (f32x4*)out;
    float* idx_out = out + (size_t)P * D;
    float* counts  = idx_out + P;

    // Counts must start at 0 every replay (harness poisons once, never again).
    (void)hipMemsetAsync(counts, 0, (size_t)V * sizeof(float), stream);

    const int block = 256;             // 4 waves/block
    const int grid  = 2048;            // 8192 waves = 32/CU, full occupancy
    RaycastFeatures_42597485641917_kernel<<<grid, block, 0, stream>>>(
        (const f32x4*)feat, idx, proj, idx_out, counts, P);
}

// Round 4
// 109.431 us; speedup vs baseline: 1.1097x; 1.1097x over previous
//
#include <hip/hip_runtime.h>

#define IGNORE_LABEL (-100)

typedef float f32x4 __attribute__((ext_vector_type(4)));

// d_out layout (flat float32): [P*128 proj | P idx passthrough | V counts]
//
// 32 lanes per pixel row (32 x 16B = 512 B, fully coalesced; wave = 2 pixels
// = 1 KB contiguous store). Branch-free gather: invalid pixels read voxel 0
// (one hot 512 B row, stays in L1 -> no extra HBM traffic) and the result is
// zeroed via cndmask. This removes the exec-mask branch around the load so
// the compiler can keep multiple gathers in flight. Manual 2x unroll issues
// both gathers before either store.
__global__ void RaycastFeatures_42597485641917_kernel(
        const f32x4* __restrict__ feat,   // [V][32] f32x4 view of [V][128] f32
        const int*   __restrict__ idx,    // [P]
        f32x4*       __restrict__ proj,   // [P][32] f32x4 view
        float*       __restrict__ idx_out,// [P]
        float*       __restrict__ counts, // [V], pre-zeroed
        int P) {
    const int tid  = blockIdx.x * blockDim.x + threadIdx.x;
    const int lane = tid & 31;
    const int grp0 = tid >> 5;
    const int ngrp = (gridDim.x * blockDim.x) >> 5;

    int p = grp0;
    for (; p + ngrp < P; p += 2 * ngrp) {
        const int p0 = p, p1 = p + ngrp;
        const int v0 = idx[p0];
        const int v1 = idx[p1];
        const bool valid0 = (v0 != IGNORE_LABEL);
        const bool valid1 = (v1 != IGNORE_LABEL);
        const int s0 = valid0 ? v0 : 0;
        const int s1 = valid1 ? v1 : 0;

        // issue both gathers before any store
        f32x4 a = feat[(size_t)s0 * 32 + lane];
        f32x4 b = feat[(size_t)s1 * 32 + lane];
        if (!valid0) a = (f32x4)(0.f);
        if (!valid1) b = (f32x4)(0.f);

        proj[(size_t)p0 * 32 + lane] = a;
        proj[(size_t)p1 * 32 + lane] = b;

        if (lane == 0) {
            idx_out[p0] = (float)v0;
            idx_out[p1] = (float)v1;
            if (valid0) atomicAdd(&counts[v0], 1.0f);
            if (valid1) atomicAdd(&counts[v1], 1.0f);
        }
    }
    for (; p < P; p += ngrp) {
        const int v = idx[p];
        const bool valid = (v != IGNORE_LABEL);
        const int s = valid ? v : 0;
        f32x4 a = feat[(size_t)s * 32 + lane];
        if (!valid) a = (f32x4)(0.f);
        proj[(size_t)p * 32 + lane] = a;
        if (lane == 0) {
            idx_out[p] = (float)v;
            if (valid) atomicAdd(&counts[v], 1.0f);
        }
    }
}

extern "C" void kernel_launch(void* const* d_in, const int* in_sizes, int n_in,
                              void* d_out, int out_size, void* d_ws, size_t ws_size,
                              hipStream_t stream) {
    const float* feat = (const float*)d_in[0];   // [V,128] f32
    const int*   idx  = (const int*)d_in[1];     // [B,NV,H,W] i32 flattened

    const int D = 128;
    const int V = in_sizes[0] / D;     // 100000
    const int P = in_sizes[1];         // 614400

    float* out     = (float*)d_out;
    f32x4* proj    = (f32x4*)out;
    float* idx_out = out + (size_t)P * D;
    float* counts  = idx_out + P;

    // Counts must start at 0 every replay (harness poisons once, never again).
    (void)hipMemsetAsync(counts, 0, (size_t)V * sizeof(float), stream);

    const int block = 256;             // 4 waves/block
    const int grid  = 2048;            // 8192 waves = 32/CU, full occupancy
    RaycastFeatures_42597485641917_kernel<<<grid, block, 0, stream>>>(
        (const f32x4*)feat, idx, proj, idx_out, counts, P);
}